// Round 3
// baseline (312.104 us; speedup 1.0000x reference)
//
#include <hip/hip_runtime.h>
#include <hip/hip_bf16.h>
#include <stdint.h>

#define S_LEN 2048
#define DM 1024
#define NH 16
#define HD 64

typedef __bf16 bf16x8 __attribute__((ext_vector_type(8)));
typedef float f32x4 __attribute__((ext_vector_type(4)));
typedef unsigned short u16x4 __attribute__((ext_vector_type(4)));

#if __has_builtin(__builtin_amdgcn_exp2f)
#define EXP2F(x) __builtin_amdgcn_exp2f(x)
#else
#define EXP2F(x) exp2f(x)
#endif

__device__ __forceinline__ unsigned short f2bf(float f){
  union { float f; uint32_t u; } v; v.f = f;
  uint32_t r = v.u + 0x7fffu + ((v.u >> 16) & 1u);
  return (unsigned short)(r >> 16);
}

__device__ __forceinline__ void load_lds16(const void* g, void* l){
  __builtin_amdgcn_global_load_lds((const __attribute__((address_space(1))) void*)g,
                                   (__attribute__((address_space(3))) void*)l, 16, 0, 0);
}

__device__ __forceinline__ f32x4 mfma16(bf16x8 a, bf16x8 b, f32x4 c){
  return __builtin_amdgcn_mfma_f32_16x16x32_bf16(a, b, c, 0, 0, 0);
}

// rows are 64 bf16 = 128B; swizzle byte_off ^= ((row&7)<<4) to break the 128B-stride bank conflict
__device__ __forceinline__ bf16x8 lds_swz_read(const unsigned short* base, int row, int cb){
  int addr = (row << 7) + (cb ^ ((row & 7) << 4));
  return *reinterpret_cast<const bf16x8*>(reinterpret_cast<const char*>(base) + addr);
}

// ---------------- prep: f32 -> bf16 for x and the 4 weight matrices ----------------
__global__ void prep_kernel(const float* __restrict__ x,
                            const float* __restrict__ wq, const float* __restrict__ wk,
                            const float* __restrict__ wv, const float* __restrict__ wo,
                            unsigned short* __restrict__ ws_base){
  long idx = ((long)blockIdx.x * 256 + threadIdx.x) * 4;
  const float* s; unsigned short* d; long off;
  if (idx < (1L << 22)) { s = x; d = ws_base; off = idx; }
  else {
    long r = idx - (1L << 22);
    int wsel = (int)(r >> 20);
    off = r & ((1L << 20) - 1);
    s = wsel == 0 ? wq : wsel == 1 ? wk : wsel == 2 ? wv : wo;
    d = ws_base + (1L << 22) + ((long)wsel << 20);
  }
  float4 f = *reinterpret_cast<const float4*>(s + off);
  u16x4 o;
  o[0] = f2bf(f.x); o[1] = f2bf(f.y); o[2] = f2bf(f.z); o[3] = f2bf(f.w);
  *reinterpret_cast<u16x4*>(d + off) = o;
}

// ---------------- GEMM: C = A[M,1024] * B[N,1024]^T + bias ----------------
// MODE 0: fused QKV (A = x_bf16). grid.x = 24: nb>>3 selects Q/K/V. Q,K stored [B,H,S,64]; V stored [B,H,64,S].
// MODE 1: output projection (A = ctx_bf16), f32 flat output.
template<int MODE>
__global__ __launch_bounds__(256, 2)
void gemm_bt_kernel(const unsigned short* __restrict__ A,
                    const unsigned short* __restrict__ B0,
                    const unsigned short* __restrict__ B1,
                    const unsigned short* __restrict__ B2,
                    const float* __restrict__ bias0,
                    const float* __restrict__ bias1,
                    const float* __restrict__ bias2,
                    unsigned short* __restrict__ q_out,
                    unsigned short* __restrict__ k_out,
                    unsigned short* __restrict__ vt_out,
                    float* __restrict__ f_out)
{
  __shared__ unsigned short As[128 * 64];
  __shared__ unsigned short Bs[128 * 64];
  const int tid = threadIdx.x;
  const int lane = tid & 63;
  const int w = tid >> 6;
  const int wr = w >> 1, wc = w & 1;
  const int mBase = blockIdx.y * 128;
  int nb = blockIdx.x;
  const unsigned short* Bmat; const float* bias; int mat;
  if constexpr (MODE == 0) {
    mat = nb >> 3;
    nb &= 7;
    Bmat = mat == 0 ? B0 : (mat == 1 ? B1 : B2);
    bias = mat == 0 ? bias0 : (mat == 1 ? bias1 : bias2);
  } else { mat = 0; Bmat = B0; bias = bias0; }
  const int nBase = nb * 128;

  f32x4 acc[4][4] = {};
  const int srow = lane >> 3;                 // row within 8-row chunk
  const int ksrc = ((lane & 7) ^ srow) * 8;   // pre-swizzled source k-offset (elements)
  const unsigned short* ArowBase = A    + (size_t)(mBase + w * 32 + srow) * DM + ksrc;
  const unsigned short* BrowBase = Bmat + (size_t)(nBase + w * 32 + srow) * DM + ksrc;

  for (int kt = 0; kt < 16; ++kt) {
    #pragma unroll
    for (int i = 0; i < 4; ++i) {
      load_lds16(ArowBase + (size_t)(i * 8) * DM + kt * 64, &As[(w * 4 + i) * 512]);
      load_lds16(BrowBase + (size_t)(i * 8) * DM + kt * 64, &Bs[(w * 4 + i) * 512]);
    }
    __syncthreads();
    #pragma unroll
    for (int kk = 0; kk < 2; ++kk) {
      bf16x8 af[4], bfr[4];
      const int cb = kk * 64 + ((lane >> 4) << 4);
      #pragma unroll
      for (int m = 0; m < 4; ++m)
        af[m] = lds_swz_read(As, wr * 64 + m * 16 + (lane & 15), cb);
      #pragma unroll
      for (int n = 0; n < 4; ++n)
        bfr[n] = lds_swz_read(Bs, wc * 64 + n * 16 + (lane & 15), cb);
      #pragma unroll
      for (int m = 0; m < 4; ++m)
        #pragma unroll
        for (int n = 0; n < 4; ++n)
          acc[m][n] = mfma16(af[m], bfr[n], acc[m][n]);
    }
    __syncthreads();
  }

  // epilogue: bias + store
  #pragma unroll
  for (int m = 0; m < 4; ++m) {
    #pragma unroll
    for (int n = 0; n < 4; ++n) {
      const int col = nBase + wc * 64 + n * 16 + (lane & 15);
      const float bv = bias[col];
      const int row0 = mBase + wr * 64 + m * 16 + ((lane >> 4) << 2);
      if constexpr (MODE == 1) {
        #pragma unroll
        for (int j = 0; j < 4; ++j)
          f_out[(size_t)(row0 + j) * DM + col] = acc[m][n][j] + bv;
      } else {
        const int h = col >> 6, d = col & 63;
        if (mat < 2) {
          unsigned short* dst = (mat == 0) ? q_out : k_out;
          #pragma unroll
          for (int j = 0; j < 4; ++j) {
            const int row = row0 + j;
            const int b = row >> 11, s = row & 2047;
            dst[(((size_t)b * NH + h) * S_LEN + s) * HD + d] = f2bf(acc[m][n][j] + bv);
          }
        } else {
          const int b = row0 >> 11, s = row0 & 2047;
          u16x4 pk;
          #pragma unroll
          for (int j = 0; j < 4; ++j) pk[j] = f2bf(acc[m][n][j] + bv);
          *reinterpret_cast<u16x4*>(&vt_out[(((size_t)b * NH + h) * HD + d) * S_LEN + s]) = pk;
        }
      }
    }
  }
}

// ---------------- flash attention (transposed-score form, bias-prefetch pipeline) ----------------
// 1-D grid of 1024 blocks, XCD-chunked so the (b=0,b=1) pair sharing bias rows lands
// on the same XCD (L2 reuse). Block = 4 waves x 16 q-rows; KV tile = 64.
// Scores computed transposed: sc = mfma(K,Q): lane holds 4 consecutive k at fixed q=lane&15.
// bias/mask for tile t+1 are register-prefetched during tile t's compute (two named
// reg sets, loop processes 2 tiles/iteration -> all indexing static).
__global__ __launch_bounds__(256, 4)
void attn_kernel(const unsigned short* __restrict__ Q,
                 const unsigned short* __restrict__ Kmat,
                 const unsigned short* __restrict__ Vt,
                 const float* __restrict__ rel_bias,
                 const float* __restrict__ mask,
                 unsigned short* __restrict__ ctx)
{
  __shared__ unsigned short Ks[2][64 * 64];
  __shared__ unsigned short Vs[2][64 * 64];
  __shared__ unsigned short Ps[4][16 * 64];

  // XCD-chunked bijective remap: 1024 = 8 XCDs x 128; b is fastest in logical id
  const int logical = (blockIdx.x & 7) * 128 + (blockIdx.x >> 3);
  const int b  = logical & 1;
  const int qt = (logical >> 1) & 31;
  const int h  = logical >> 6;

  const int lane = threadIdx.x & 63, w = threadIdx.x >> 6;
  const int q = lane & 15, g = lane >> 4;
  const size_t bh = (size_t)b * NH + h;
  const int qRow = qt * 64 + w * 16;
  const unsigned short* Qp = Q + (bh * S_LEN + qRow) * HD;
  bf16x8 qf0 = *reinterpret_cast<const bf16x8*>(Qp + (size_t)q * HD + g * 8);
  bf16x8 qf1 = *reinterpret_cast<const bf16x8*>(Qp + (size_t)q * HD + 32 + g * 8);

  const unsigned short* Kp = Kmat + bh * (size_t)S_LEN * HD;
  const unsigned short* Vp = Vt + bh * (size_t)HD * S_LEN;
  const float* bp = rel_bias + (size_t)h * S_LEN * S_LEN + (size_t)(qRow + q) * S_LEN;
  const float* mp = mask + (size_t)(qRow + q) * S_LEN;

  float m_run = -3.0e38f, l_run = 0.f;
  f32x4 acc[4] = {};

  const float SC  = 0.125f * 1.44269504089f;  // head scale * log2(e)
  const float L2E = 1.44269504089f;

  const int srow = lane >> 3;
  const int ksrc = ((lane & 7) ^ srow) * 8;   // pre-swizzled global k-offset
  const int cbq = g << 4;

  auto load_bm = [&](int kvBase, float4 (&b4)[4], float4 (&m4)[4]) {
    #pragma unroll
    for (int n = 0; n < 4; ++n) {
      b4[n] = *reinterpret_cast<const float4*>(bp + kvBase + n * 16 + g * 4);
      m4[n] = *reinterpret_cast<const float4*>(mp + kvBase + n * 16 + g * 4);
    }
  };

  auto stage = [&](int kvBase, int buf) {
    #pragma unroll
    for (int i = 0; i < 2; ++i) {
      const int chunk = w * 2 + i;
      const int row = chunk * 8 + srow;
      load_lds16(Kp + (size_t)(kvBase + row) * HD + ksrc, &Ks[buf][chunk * 512]);
      load_lds16(Vp + (size_t)row * S_LEN + kvBase + ksrc, &Vs[buf][chunk * 512]);
    }
  };

  auto compute_tile = [&](const unsigned short* Ksb, const unsigned short* Vsb,
                          const float4 (&b4)[4], const float4 (&m4)[4]) {
    // QK^T (transposed): sc[n] holds scores^T[k][q]
    f32x4 sc[4];
    #pragma unroll
    for (int n = 0; n < 4; ++n) {
      const int row = n * 16 + q;
      bf16x8 kf0 = lds_swz_read(Ksb, row, cbq);
      bf16x8 kf1 = lds_swz_read(Ksb, row, 64 + cbq);
      f32x4 z = {};
      z = mfma16(kf0, qf0, z);
      sc[n] = mfma16(kf1, qf1, z);
    }

    // to exp2 domain with bias + mask
    float t[4][4];
    float mt = -3.0e38f;
    #pragma unroll
    for (int n = 0; n < 4; ++n) {
      #pragma unroll
      for (int j = 0; j < 4; ++j) {
        const float bm = ((const float*)&b4[n])[j] + ((const float*)&m4[n])[j];
        const float fv = sc[n][j] * SC + bm * L2E;
        t[n][j] = fv;
        mt = fmaxf(mt, fv);
      }
    }
    mt = fmaxf(mt, __shfl_xor(mt, 16));
    mt = fmaxf(mt, __shfl_xor(mt, 32));
    const float mn = fmaxf(m_run, mt);
    const float corr = EXP2F(m_run - mn);
    m_run = mn;
    float ls = 0.f;
    #pragma unroll
    for (int n = 0; n < 4; ++n)
      #pragma unroll
      for (int j = 0; j < 4; ++j) {
        const float p = EXP2F(t[n][j] - mn);
        t[n][j] = p;
        ls += p;
      }
    ls += __shfl_xor(ls, 16);
    ls += __shfl_xor(ls, 32);
    l_run = l_run * corr + ls;
    #pragma unroll
    for (int n = 0; n < 4; ++n) acc[n] *= corr;

    // P^T frag -> per-wave swizzled LDS, reread as B-fragment
    unsigned short* Pw = Ps[w];
    #pragma unroll
    for (int n = 0; n < 4; ++n) {
      u16x4 pk;
      #pragma unroll
      for (int j = 0; j < 4; ++j) pk[j] = f2bf(t[n][j]);
      const int colb = (n * 16 + 4 * g) * 2;
      *reinterpret_cast<u16x4*>(
          reinterpret_cast<char*>(Pw) + (q << 7) + (colb ^ ((q & 7) << 4))) = pk;
    }
    bf16x8 pf0 = lds_swz_read(Pw, q, cbq);
    bf16x8 pf1 = lds_swz_read(Pw, q, 64 + cbq);
    // ctx^T[d][q] += Vt * P^T
    #pragma unroll
    for (int n = 0; n < 4; ++n) {
      bf16x8 vf0 = lds_swz_read(Vsb, n * 16 + q, cbq);
      bf16x8 vf1 = lds_swz_read(Vsb, n * 16 + q, 64 + cbq);
      acc[n] = mfma16(vf0, pf0, acc[n]);
      acc[n] = mfma16(vf1, pf1, acc[n]);
    }
  };

  float4 b4A[4], m4A[4], b4B[4], m4B[4];

  // prologue: bias tile0 + KV tile0 -> buf0
  load_bm(0, b4A, m4A);
  stage(0, 0);
  __syncthreads();

  for (int i = 0; i < 16; ++i) {
    const int t0 = 2 * i;
    // prefetch tile t0+1: bias into regs B, KV into buf1 (overlaps compute t0)
    load_bm((t0 + 1) * 64, b4B, m4B);
    stage((t0 + 1) * 64, 1);
    compute_tile(Ks[0], Vs[0], b4A, m4A);
    __syncthreads();
    // prefetch tile t0+2: bias into regs A, KV into buf0 (overlaps compute t0+1)
    if (i < 15) {
      load_bm((t0 + 2) * 64, b4A, m4A);
      stage((t0 + 2) * 64, 0);
    }
    compute_tile(Ks[1], Vs[1], b4B, m4B);
    __syncthreads();
  }

  // epilogue: normalize, redistribute through per-wave LDS, coalesced 16B stores
  const float inv = 1.0f / l_run;
  unsigned short* Pw = Ps[w];
  #pragma unroll
  for (int n = 0; n < 4; ++n) {
    u16x4 pk;
    #pragma unroll
    for (int j = 0; j < 4; ++j) pk[j] = f2bf(acc[n][j] * inv);
    const int colb = (n * 16 + 4 * g) * 2;
    *reinterpret_cast<u16x4*>(
        reinterpret_cast<char*>(Pw) + (q << 7) + (colb ^ ((q & 7) << 4))) = pk;
  }
  bf16x8 c0 = lds_swz_read(Pw, q, g << 4);
  bf16x8 c1 = lds_swz_read(Pw, q, 64 + (g << 4));
  unsigned short* cp = ctx + ((size_t)b * S_LEN + qRow + q) * DM + h * HD;
  *reinterpret_cast<bf16x8*>(cp + 8 * g) = c0;
  *reinterpret_cast<bf16x8*>(cp + 32 + 8 * g) = c1;
}

extern "C" void kernel_launch(void* const* d_in, const int* in_sizes, int n_in,
                              void* d_out, int out_size, void* d_ws, size_t ws_size,
                              hipStream_t stream) {
  (void)in_sizes; (void)n_in; (void)out_size; (void)ws_size;
  const float* x  = (const float*)d_in[0];
  const float* rb = (const float*)d_in[1];
  const float* mk = (const float*)d_in[2];
  const float* Wq = (const float*)d_in[3];
  const float* bq = (const float*)d_in[4];
  const float* Wk = (const float*)d_in[5];
  const float* bk = (const float*)d_in[6];
  const float* Wv = (const float*)d_in[7];
  const float* bv = (const float*)d_in[8];
  const float* Wo = (const float*)d_in[9];
  const float* bo = (const float*)d_in[10];
  float* out = (float*)d_out;

  unsigned short* ws  = (unsigned short*)d_ws;
  unsigned short* xb  = ws;                       // 4M elems
  unsigned short* wqb = ws + (1L << 22);          // 1M
  unsigned short* wkb = wqb + (1L << 20);
  unsigned short* wvb = wkb + (1L << 20);
  unsigned short* wob = wvb + (1L << 20);
  unsigned short* Qw  = wob + (1L << 20);         // 4M [B,H,S,64]
  unsigned short* Kw  = Qw + (1L << 22);          // 4M [B,H,S,64]
  unsigned short* Vtw = Kw + (1L << 22);          // 4M [B,H,64,S]
  unsigned short* ctx = Vtw + (1L << 22);         // 4M [B,S,DM]

  prep_kernel<<<8192, 256, 0, stream>>>(x, Wq, Wk, Wv, Wo, ws);
  gemm_bt_kernel<0><<<dim3(24, 32), 256, 0, stream>>>(
      xb, wqb, wkb, wvb, bq, bk, bv, Qw, Kw, Vtw, nullptr);
  attn_kernel<<<1024, 256, 0, stream>>>(Qw, Kw, Vtw, rb, mk, ctx);
  gemm_bt_kernel<1><<<dim3(8, 32), 256, 0, stream>>>(
      ctx, wob, nullptr, nullptr, bo, nullptr, nullptr, nullptr, nullptr, nullptr, out);
}

// Round 4
// 261.824 us; speedup vs baseline: 1.1920x; 1.1920x over previous
//
#include <hip/hip_runtime.h>
#include <hip/hip_bf16.h>
#include <stdint.h>

#define S_LEN 2048
#define DM 1024
#define NH 16
#define HD 64

typedef __bf16 bf16x8 __attribute__((ext_vector_type(8)));
typedef float f32x4 __attribute__((ext_vector_type(4)));
typedef unsigned short u16x4 __attribute__((ext_vector_type(4)));

#if __has_builtin(__builtin_amdgcn_exp2f)
#define EXP2F(x) __builtin_amdgcn_exp2f(x)
#else
#define EXP2F(x) exp2f(x)
#endif

__device__ __forceinline__ unsigned short f2bf(float f){
  union { float f; uint32_t u; } v; v.f = f;
  uint32_t r = v.u + 0x7fffu + ((v.u >> 16) & 1u);
  return (unsigned short)(r >> 16);
}

__device__ __forceinline__ void load_lds16(const void* g, void* l){
  __builtin_amdgcn_global_load_lds((const __attribute__((address_space(1))) void*)g,
                                   (__attribute__((address_space(3))) void*)l, 16, 0, 0);
}

__device__ __forceinline__ f32x4 mfma16(bf16x8 a, bf16x8 b, f32x4 c){
  return __builtin_amdgcn_mfma_f32_16x16x32_bf16(a, b, c, 0, 0, 0);
}

// rows are 64 bf16 = 128B; swizzle byte_off ^= ((row&7)<<4) to break the 128B-stride bank conflict
__device__ __forceinline__ bf16x8 lds_swz_read(const unsigned short* base, int row, int cb){
  int addr = (row << 7) + (cb ^ ((row & 7) << 4));
  return *reinterpret_cast<const bf16x8*>(reinterpret_cast<const char*>(base) + addr);
}

// ---------------- prep: f32 -> bf16 for x and the 4 weight matrices ----------------
__global__ void prep_kernel(const float* __restrict__ x,
                            const float* __restrict__ wq, const float* __restrict__ wk,
                            const float* __restrict__ wv, const float* __restrict__ wo,
                            unsigned short* __restrict__ ws_base){
  long idx = ((long)blockIdx.x * 256 + threadIdx.x) * 4;
  const float* s; unsigned short* d; long off;
  if (idx < (1L << 22)) { s = x; d = ws_base; off = idx; }
  else {
    long r = idx - (1L << 22);
    int wsel = (int)(r >> 20);
    off = r & ((1L << 20) - 1);
    s = wsel == 0 ? wq : wsel == 1 ? wk : wsel == 2 ? wv : wo;
    d = ws_base + (1L << 22) + ((long)wsel << 20);
  }
  float4 f = *reinterpret_cast<const float4*>(s + off);
  u16x4 o;
  o[0] = f2bf(f.x); o[1] = f2bf(f.y); o[2] = f2bf(f.z); o[3] = f2bf(f.w);
  *reinterpret_cast<u16x4*>(d + off) = o;
}

// ---------------- GEMM: C = A[M,1024] * B[N,1024]^T + bias ----------------
// MODE 0: fused QKV (A = x_bf16). grid.x = 24: nb>>3 selects Q/K/V. Q,K stored [B,H,S,64]; V stored [B,H,64,S].
// MODE 1: output projection (A = ctx_bf16), f32 flat output.
template<int MODE>
__global__ __launch_bounds__(256, 2)
void gemm_bt_kernel(const unsigned short* __restrict__ A,
                    const unsigned short* __restrict__ B0,
                    const unsigned short* __restrict__ B1,
                    const unsigned short* __restrict__ B2,
                    const float* __restrict__ bias0,
                    const float* __restrict__ bias1,
                    const float* __restrict__ bias2,
                    unsigned short* __restrict__ q_out,
                    unsigned short* __restrict__ k_out,
                    unsigned short* __restrict__ vt_out,
                    float* __restrict__ f_out)
{
  __shared__ unsigned short As[128 * 64];
  __shared__ unsigned short Bs[128 * 64];
  const int tid = threadIdx.x;
  const int lane = tid & 63;
  const int w = tid >> 6;
  const int wr = w >> 1, wc = w & 1;
  const int mBase = blockIdx.y * 128;
  int nb = blockIdx.x;
  const unsigned short* Bmat; const float* bias; int mat;
  if constexpr (MODE == 0) {
    mat = nb >> 3;
    nb &= 7;
    Bmat = mat == 0 ? B0 : (mat == 1 ? B1 : B2);
    bias = mat == 0 ? bias0 : (mat == 1 ? bias1 : bias2);
  } else { mat = 0; Bmat = B0; bias = bias0; }
  const int nBase = nb * 128;

  f32x4 acc[4][4] = {};
  const int srow = lane >> 3;                 // row within 8-row chunk
  const int ksrc = ((lane & 7) ^ srow) * 8;   // pre-swizzled source k-offset (elements)
  const unsigned short* ArowBase = A    + (size_t)(mBase + w * 32 + srow) * DM + ksrc;
  const unsigned short* BrowBase = Bmat + (size_t)(nBase + w * 32 + srow) * DM + ksrc;

  for (int kt = 0; kt < 16; ++kt) {
    #pragma unroll
    for (int i = 0; i < 4; ++i) {
      load_lds16(ArowBase + (size_t)(i * 8) * DM + kt * 64, &As[(w * 4 + i) * 512]);
      load_lds16(BrowBase + (size_t)(i * 8) * DM + kt * 64, &Bs[(w * 4 + i) * 512]);
    }
    __syncthreads();
    #pragma unroll
    for (int kk = 0; kk < 2; ++kk) {
      bf16x8 af[4], bfr[4];
      const int cb = kk * 64 + ((lane >> 4) << 4);
      #pragma unroll
      for (int m = 0; m < 4; ++m)
        af[m] = lds_swz_read(As, wr * 64 + m * 16 + (lane & 15), cb);
      #pragma unroll
      for (int n = 0; n < 4; ++n)
        bfr[n] = lds_swz_read(Bs, wc * 64 + n * 16 + (lane & 15), cb);
      #pragma unroll
      for (int m = 0; m < 4; ++m)
        #pragma unroll
        for (int n = 0; n < 4; ++n)
          acc[m][n] = mfma16(af[m], bfr[n], acc[m][n]);
    }
    __syncthreads();
  }

  // epilogue: bias + store
  #pragma unroll
  for (int m = 0; m < 4; ++m) {
    #pragma unroll
    for (int n = 0; n < 4; ++n) {
      const int col = nBase + wc * 64 + n * 16 + (lane & 15);
      const float bv = bias[col];
      const int row0 = mBase + wr * 64 + m * 16 + ((lane >> 4) << 2);
      if constexpr (MODE == 1) {
        #pragma unroll
        for (int j = 0; j < 4; ++j)
          f_out[(size_t)(row0 + j) * DM + col] = acc[m][n][j] + bv;
      } else {
        const int h = col >> 6, d = col & 63;
        if (mat < 2) {
          unsigned short* dst = (mat == 0) ? q_out : k_out;
          #pragma unroll
          for (int j = 0; j < 4; ++j) {
            const int row = row0 + j;
            const int b = row >> 11, s = row & 2047;
            dst[(((size_t)b * NH + h) * S_LEN + s) * HD + d] = f2bf(acc[m][n][j] + bv);
          }
        } else {
          const int b = row0 >> 11, s = row0 & 2047;
          u16x4 pk;
          #pragma unroll
          for (int j = 0; j < 4; ++j) pk[j] = f2bf(acc[m][n][j] + bv);
          *reinterpret_cast<u16x4*>(&vt_out[(((size_t)b * NH + h) * HD + d) * S_LEN + s]) = pk;
        }
      }
    }
  }
}

// ---------------- flash attention (transposed-score form, bias-prefetch pipeline) ----------------
// 1-D grid of 1024 blocks, XCD-chunked so the (b=0,b=1) pair sharing bias rows lands
// on the same XCD (L2 reuse). Block = 4 waves x 16 q-rows; KV tile = 64.
// Scores computed transposed: sc = mfma(K,Q): lane holds 4 consecutive k at fixed q=lane&15.
// (bias+mask)*log2e for tile t+1 is register-prefetched during tile t's compute.
// All pipeline state in NAMED local arrays with static indexing; bodies are macros
// (round-3's lambda/by-ref version was demoted to scratch: VGPR 64, WRITE_SIZE 217MB).

#define LOAD_BM(kvB, bm) do {                                                               \
    bm[0] = (*(const f32x4*)(bp + (kvB) + g * 4)      + *(const f32x4*)(mp + (kvB) + g * 4))      * L2E; \
    bm[1] = (*(const f32x4*)(bp + (kvB) + 16 + g * 4) + *(const f32x4*)(mp + (kvB) + 16 + g * 4)) * L2E; \
    bm[2] = (*(const f32x4*)(bp + (kvB) + 32 + g * 4) + *(const f32x4*)(mp + (kvB) + 32 + g * 4)) * L2E; \
    bm[3] = (*(const f32x4*)(bp + (kvB) + 48 + g * 4) + *(const f32x4*)(mp + (kvB) + 48 + g * 4)) * L2E; \
  } while (0)

#define STAGE(kvB, buf) do {                                                                \
    load_lds16(Kp + (size_t)((kvB) + w * 16 + srow) * HD + ksrc,      &Ks[buf][(w * 2) * 512]);     \
    load_lds16(Vp + (size_t)(w * 16 + srow) * S_LEN + (kvB) + ksrc,   &Vs[buf][(w * 2) * 512]);     \
    load_lds16(Kp + (size_t)((kvB) + w * 16 + 8 + srow) * HD + ksrc,  &Ks[buf][(w * 2 + 1) * 512]); \
    load_lds16(Vp + (size_t)(w * 16 + 8 + srow) * S_LEN + (kvB) + ksrc, &Vs[buf][(w * 2 + 1) * 512]); \
  } while (0)

#define COMPUTE_TILE(KSB, VSB, BM) do {                                                     \
    f32x4 sc_[4];                                                                           \
    _Pragma("unroll")                                                                       \
    for (int n = 0; n < 4; ++n) {                                                           \
      const int row_ = n * 16 + q;                                                          \
      bf16x8 kf0_ = lds_swz_read(KSB, row_, cbq);                                           \
      bf16x8 kf1_ = lds_swz_read(KSB, row_, 64 + cbq);                                      \
      f32x4 z_ = {};                                                                        \
      z_ = mfma16(kf0_, qf0, z_);                                                           \
      sc_[n] = mfma16(kf1_, qf1, z_);                                                       \
    }                                                                                       \
    float t_[4][4];                                                                         \
    float mt_ = -3.0e38f;                                                                   \
    _Pragma("unroll")                                                                       \
    for (int n = 0; n < 4; ++n) {                                                           \
      _Pragma("unroll")                                                                     \
      for (int j = 0; j < 4; ++j) {                                                         \
        const float fv_ = sc_[n][j] * SC + BM[n][j];                                        \
        t_[n][j] = fv_;                                                                     \
        mt_ = fmaxf(mt_, fv_);                                                              \
      }                                                                                     \
    }                                                                                       \
    mt_ = fmaxf(mt_, __shfl_xor(mt_, 16));                                                  \
    mt_ = fmaxf(mt_, __shfl_xor(mt_, 32));                                                  \
    const float mn_ = fmaxf(m_run, mt_);                                                    \
    const float corr_ = EXP2F(m_run - mn_);                                                 \
    m_run = mn_;                                                                            \
    float ls_ = 0.f;                                                                        \
    _Pragma("unroll")                                                                       \
    for (int n = 0; n < 4; ++n)                                                             \
      _Pragma("unroll")                                                                     \
      for (int j = 0; j < 4; ++j) {                                                         \
        const float p_ = EXP2F(t_[n][j] - mn_);                                             \
        t_[n][j] = p_;                                                                      \
        ls_ += p_;                                                                          \
      }                                                                                     \
    ls_ += __shfl_xor(ls_, 16);                                                             \
    ls_ += __shfl_xor(ls_, 32);                                                             \
    l_run = l_run * corr_ + ls_;                                                            \
    _Pragma("unroll")                                                                       \
    for (int n = 0; n < 4; ++n) acc[n] *= corr_;                                            \
    unsigned short* Pw_ = Ps[w];                                                            \
    _Pragma("unroll")                                                                       \
    for (int n = 0; n < 4; ++n) {                                                           \
      u16x4 pk_;                                                                            \
      _Pragma("unroll")                                                                     \
      for (int j = 0; j < 4; ++j) pk_[j] = f2bf(t_[n][j]);                                  \
      const int colb_ = (n * 16 + 4 * g) * 2;                                               \
      *reinterpret_cast<u16x4*>(                                                            \
          reinterpret_cast<char*>(Pw_) + (q << 7) + (colb_ ^ ((q & 7) << 4))) = pk_;        \
    }                                                                                       \
    bf16x8 pf0_ = lds_swz_read(Pw_, q, cbq);                                                \
    bf16x8 pf1_ = lds_swz_read(Pw_, q, 64 + cbq);                                           \
    _Pragma("unroll")                                                                       \
    for (int n = 0; n < 4; ++n) {                                                           \
      bf16x8 vf0_ = lds_swz_read(VSB, n * 16 + q, cbq);                                     \
      bf16x8 vf1_ = lds_swz_read(VSB, n * 16 + q, 64 + cbq);                                \
      acc[n] = mfma16(vf0_, pf0_, acc[n]);                                                  \
      acc[n] = mfma16(vf1_, pf1_, acc[n]);                                                  \
    }                                                                                       \
  } while (0)

__global__ __launch_bounds__(256, 4)
void attn_kernel(const unsigned short* __restrict__ Q,
                 const unsigned short* __restrict__ Kmat,
                 const unsigned short* __restrict__ Vt,
                 const float* __restrict__ rel_bias,
                 const float* __restrict__ mask,
                 unsigned short* __restrict__ ctx)
{
  __shared__ unsigned short Ks[2][64 * 64];
  __shared__ unsigned short Vs[2][64 * 64];
  __shared__ unsigned short Ps[4][16 * 64];

  // XCD-chunked bijective remap: 1024 = 8 XCDs x 128; b is fastest in logical id
  const int logical = (blockIdx.x & 7) * 128 + (blockIdx.x >> 3);
  const int b  = logical & 1;
  const int qt = (logical >> 1) & 31;
  const int h  = logical >> 6;

  const int lane = threadIdx.x & 63, w = threadIdx.x >> 6;
  const int q = lane & 15, g = lane >> 4;
  const size_t bh = (size_t)b * NH + h;
  const int qRow = qt * 64 + w * 16;
  const unsigned short* Qp = Q + (bh * S_LEN + qRow) * HD;
  bf16x8 qf0 = *reinterpret_cast<const bf16x8*>(Qp + (size_t)q * HD + g * 8);
  bf16x8 qf1 = *reinterpret_cast<const bf16x8*>(Qp + (size_t)q * HD + 32 + g * 8);

  const unsigned short* Kp = Kmat + bh * (size_t)S_LEN * HD;
  const unsigned short* Vp = Vt + bh * (size_t)HD * S_LEN;
  const float* bp = rel_bias + (size_t)h * S_LEN * S_LEN + (size_t)(qRow + q) * S_LEN;
  const float* mp = mask + (size_t)(qRow + q) * S_LEN;

  float m_run = -3.0e38f, l_run = 0.f;
  f32x4 acc[4] = {};

  const float SC  = 0.125f * 1.44269504089f;  // head scale * log2(e)
  const float L2E = 1.44269504089f;

  const int srow = lane >> 3;
  const int ksrc = ((lane & 7) ^ srow) * 8;   // pre-swizzled global k-offset
  const int cbq = g << 4;

  f32x4 bmA[4], bmB[4];

  // prologue: bias tile0 + KV tile0 -> buf0
  LOAD_BM(0, bmA);
  STAGE(0, 0);
  __syncthreads();

  for (int i = 0; i < 16; ++i) {
    const int t0 = 2 * i;
    // prefetch tile t0+1: bm into B regs, KV into buf1 (overlaps compute t0)
    LOAD_BM((t0 + 1) * 64, bmB);
    STAGE((t0 + 1) * 64, 1);
    COMPUTE_TILE(Ks[0], Vs[0], bmA);
    __syncthreads();
    // prefetch tile t0+2: bm into A regs, KV into buf0 (overlaps compute t0+1)
    if (i < 15) {
      LOAD_BM((t0 + 2) * 64, bmA);
      STAGE((t0 + 2) * 64, 0);
    }
    COMPUTE_TILE(Ks[1], Vs[1], bmB);
    __syncthreads();
  }

  // epilogue: normalize, redistribute through per-wave LDS, coalesced 16B stores
  const float inv = 1.0f / l_run;
  unsigned short* Pw = Ps[w];
  #pragma unroll
  for (int n = 0; n < 4; ++n) {
    u16x4 pk;
    #pragma unroll
    for (int j = 0; j < 4; ++j) pk[j] = f2bf(acc[n][j] * inv);
    const int colb = (n * 16 + 4 * g) * 2;
    *reinterpret_cast<u16x4*>(
        reinterpret_cast<char*>(Pw) + (q << 7) + (colb ^ ((q & 7) << 4))) = pk;
  }
  bf16x8 c0 = lds_swz_read(Pw, q, g << 4);
  bf16x8 c1 = lds_swz_read(Pw, q, 64 + (g << 4));
  unsigned short* cp = ctx + ((size_t)b * S_LEN + qRow + q) * DM + h * HD;
  *reinterpret_cast<bf16x8*>(cp + 8 * g) = c0;
  *reinterpret_cast<bf16x8*>(cp + 32 + 8 * g) = c1;
}

extern "C" void kernel_launch(void* const* d_in, const int* in_sizes, int n_in,
                              void* d_out, int out_size, void* d_ws, size_t ws_size,
                              hipStream_t stream) {
  (void)in_sizes; (void)n_in; (void)out_size; (void)ws_size;
  const float* x  = (const float*)d_in[0];
  const float* rb = (const float*)d_in[1];
  const float* mk = (const float*)d_in[2];
  const float* Wq = (const float*)d_in[3];
  const float* bq = (const float*)d_in[4];
  const float* Wk = (const float*)d_in[5];
  const float* bk = (const float*)d_in[6];
  const float* Wv = (const float*)d_in[7];
  const float* bv = (const float*)d_in[8];
  const float* Wo = (const float*)d_in[9];
  const float* bo = (const float*)d_in[10];
  float* out = (float*)d_out;

  unsigned short* ws  = (unsigned short*)d_ws;
  unsigned short* xb  = ws;                       // 4M elems
  unsigned short* wqb = ws + (1L << 22);          // 1M
  unsigned short* wkb = wqb + (1L << 20);
  unsigned short* wvb = wkb + (1L << 20);
  unsigned short* wob = wvb + (1L << 20);
  unsigned short* Qw  = wob + (1L << 20);         // 4M [B,H,S,64]
  unsigned short* Kw  = Qw + (1L << 22);          // 4M [B,H,S,64]
  unsigned short* Vtw = Kw + (1L << 22);          // 4M [B,H,64,S]
  unsigned short* ctx = Vtw + (1L << 22);         // 4M [B,S,DM]

  prep_kernel<<<8192, 256, 0, stream>>>(x, Wq, Wk, Wv, Wo, ws);
  gemm_bt_kernel<0><<<dim3(24, 32), 256, 0, stream>>>(
      xb, wqb, wkb, wvb, bq, bk, bv, Qw, Kw, Vtw, nullptr);
  attn_kernel<<<1024, 256, 0, stream>>>(Qw, Kw, Vtw, rb, mk, ctx);
  gemm_bt_kernel<1><<<dim3(8, 32), 256, 0, stream>>>(
      ctx, wob, nullptr, nullptr, bo, nullptr, nullptr, nullptr, nullptr, nullptr, out);
}

// Round 5
// 237.620 us; speedup vs baseline: 1.3135x; 1.1019x over previous
//
#include <hip/hip_runtime.h>
#include <hip/hip_bf16.h>
#include <stdint.h>

#define S_LEN 2048
#define DM 1024
#define NH 16
#define HD 64

typedef __bf16 bf16x8 __attribute__((ext_vector_type(8)));
typedef float f32x4 __attribute__((ext_vector_type(4)));
typedef unsigned short u16x4 __attribute__((ext_vector_type(4)));

#if __has_builtin(__builtin_amdgcn_exp2f)
#define EXP2F(x) __builtin_amdgcn_exp2f(x)
#else
#define EXP2F(x) exp2f(x)
#endif

__device__ __forceinline__ unsigned short f2bf(float f){
  union { float f; uint32_t u; } v; v.f = f;
  uint32_t r = v.u + 0x7fffu + ((v.u >> 16) & 1u);
  return (unsigned short)(r >> 16);
}

__device__ __forceinline__ void load_lds16(const void* g, void* l){
  __builtin_amdgcn_global_load_lds((const __attribute__((address_space(1))) void*)g,
                                   (__attribute__((address_space(3))) void*)l, 16, 0, 0);
}

__device__ __forceinline__ f32x4 mfma16(bf16x8 a, bf16x8 b, f32x4 c){
  return __builtin_amdgcn_mfma_f32_16x16x32_bf16(a, b, c, 0, 0, 0);
}

// rows are 64 bf16 = 128B; swizzle byte_off ^= ((row&7)<<4) to break the 128B-stride bank conflict
__device__ __forceinline__ bf16x8 lds_swz_read(const unsigned short* base, int row, int cb){
  int addr = (row << 7) + (cb ^ ((row & 7) << 4));
  return *reinterpret_cast<const bf16x8*>(reinterpret_cast<const char*>(base) + addr);
}

// ---------------- prep: f32 -> bf16 for x and the 4 weight matrices ----------------
__global__ void prep_kernel(const float* __restrict__ x,
                            const float* __restrict__ wq, const float* __restrict__ wk,
                            const float* __restrict__ wv, const float* __restrict__ wo,
                            unsigned short* __restrict__ ws_base){
  long idx = ((long)blockIdx.x * 256 + threadIdx.x) * 4;
  const float* s; unsigned short* d; long off;
  if (idx < (1L << 22)) { s = x; d = ws_base; off = idx; }
  else {
    long r = idx - (1L << 22);
    int wsel = (int)(r >> 20);
    off = r & ((1L << 20) - 1);
    s = wsel == 0 ? wq : wsel == 1 ? wk : wsel == 2 ? wv : wo;
    d = ws_base + (1L << 22) + ((long)wsel << 20);
  }
  float4 f = *reinterpret_cast<const float4*>(s + off);
  u16x4 o;
  o[0] = f2bf(f.x); o[1] = f2bf(f.y); o[2] = f2bf(f.z); o[3] = f2bf(f.w);
  *reinterpret_cast<u16x4*>(d + off) = o;
}

// ---------------- GEMM: C = A[M,1024] * B[N,1024]^T + bias ----------------
// MODE 0: fused QKV (A = x_bf16). grid.x = 24: nb>>3 selects Q/K/V. Q,K stored [B,H,S,64]; V stored [B,H,64,S].
// MODE 1: output projection (A = ctx_bf16), f32 flat output.
template<int MODE>
__global__ __launch_bounds__(256, 2)
void gemm_bt_kernel(const unsigned short* __restrict__ A,
                    const unsigned short* __restrict__ B0,
                    const unsigned short* __restrict__ B1,
                    const unsigned short* __restrict__ B2,
                    const float* __restrict__ bias0,
                    const float* __restrict__ bias1,
                    const float* __restrict__ bias2,
                    unsigned short* __restrict__ q_out,
                    unsigned short* __restrict__ k_out,
                    unsigned short* __restrict__ vt_out,
                    float* __restrict__ f_out)
{
  __shared__ unsigned short As[128 * 64];
  __shared__ unsigned short Bs[128 * 64];
  const int tid = threadIdx.x;
  const int lane = tid & 63;
  const int w = tid >> 6;
  const int wr = w >> 1, wc = w & 1;
  const int mBase = blockIdx.y * 128;
  int nb = blockIdx.x;
  const unsigned short* Bmat; const float* bias; int mat;
  if constexpr (MODE == 0) {
    mat = nb >> 3;
    nb &= 7;
    Bmat = mat == 0 ? B0 : (mat == 1 ? B1 : B2);
    bias = mat == 0 ? bias0 : (mat == 1 ? bias1 : bias2);
  } else { mat = 0; Bmat = B0; bias = bias0; }
  const int nBase = nb * 128;

  f32x4 acc[4][4] = {};
  const int srow = lane >> 3;                 // row within 8-row chunk
  const int ksrc = ((lane & 7) ^ srow) * 8;   // pre-swizzled source k-offset (elements)
  const unsigned short* ArowBase = A    + (size_t)(mBase + w * 32 + srow) * DM + ksrc;
  const unsigned short* BrowBase = Bmat + (size_t)(nBase + w * 32 + srow) * DM + ksrc;

  for (int kt = 0; kt < 16; ++kt) {
    #pragma unroll
    for (int i = 0; i < 4; ++i) {
      load_lds16(ArowBase + (size_t)(i * 8) * DM + kt * 64, &As[(w * 4 + i) * 512]);
      load_lds16(BrowBase + (size_t)(i * 8) * DM + kt * 64, &Bs[(w * 4 + i) * 512]);
    }
    __syncthreads();
    #pragma unroll
    for (int kk = 0; kk < 2; ++kk) {
      bf16x8 af[4], bfr[4];
      const int cb = kk * 64 + ((lane >> 4) << 4);
      #pragma unroll
      for (int m = 0; m < 4; ++m)
        af[m] = lds_swz_read(As, wr * 64 + m * 16 + (lane & 15), cb);
      #pragma unroll
      for (int n = 0; n < 4; ++n)
        bfr[n] = lds_swz_read(Bs, wc * 64 + n * 16 + (lane & 15), cb);
      #pragma unroll
      for (int m = 0; m < 4; ++m)
        #pragma unroll
        for (int n = 0; n < 4; ++n)
          acc[m][n] = mfma16(af[m], bfr[n], acc[m][n]);
    }
    __syncthreads();
  }

  // epilogue: bias + store
  #pragma unroll
  for (int m = 0; m < 4; ++m) {
    #pragma unroll
    for (int n = 0; n < 4; ++n) {
      const int col = nBase + wc * 64 + n * 16 + (lane & 15);
      const float bv = bias[col];
      const int row0 = mBase + wr * 64 + m * 16 + ((lane >> 4) << 2);
      if constexpr (MODE == 1) {
        #pragma unroll
        for (int j = 0; j < 4; ++j)
          f_out[(size_t)(row0 + j) * DM + col] = acc[m][n][j] + bv;
      } else {
        const int h = col >> 6, d = col & 63;
        if (mat < 2) {
          unsigned short* dst = (mat == 0) ? q_out : k_out;
          #pragma unroll
          for (int j = 0; j < 4; ++j) {
            const int row = row0 + j;
            const int b = row >> 11, s = row & 2047;
            dst[(((size_t)b * NH + h) * S_LEN + s) * HD + d] = f2bf(acc[m][n][j] + bv);
          }
        } else {
          const int b = row0 >> 11, s = row0 & 2047;
          u16x4 pk;
          #pragma unroll
          for (int j = 0; j < 4; ++j) pk[j] = f2bf(acc[m][n][j] + bv);
          *reinterpret_cast<u16x4*>(&vt_out[(((size_t)b * NH + h) * HD + d) * S_LEN + s]) = pk;
        }
      }
    }
  }
}

// ---------------- flash attention (transposed-score form, bias-prefetch pipeline) ----------------
// 1-D grid of 1024 blocks, XCD-chunked so the (b=0,b=1) pair sharing bias rows lands
// on the same XCD (L2 reuse). Block = 4 waves x 16 q-rows; KV tile = 64.
// Scores computed transposed: sc = mfma(K,Q): lane holds 4 consecutive k at fixed q=lane&15.
// Pipeline state lives ONLY in individually-named f32x4 vars (no arrays -> no SROA
// failure -> no scratch; rounds 3/4 spilled array state at 217/54 MB scratch traffic).
// amdgpu_waves_per_eu(3,4) pins the allocator's budget to <=170 (target 128) VGPRs:
// launch_bounds' min-waves alone let the backend target 8 waves/EU (64 VGPR) and spill.

#define LOAD_RAW(kvB) do {                                                    \
    rb0 = *reinterpret_cast<const f32x4*>(bp + (kvB) + g * 4);                \
    rm0 = *reinterpret_cast<const f32x4*>(mp + (kvB) + g * 4);                \
    rb1 = *reinterpret_cast<const f32x4*>(bp + (kvB) + 16 + g * 4);           \
    rm1 = *reinterpret_cast<const f32x4*>(mp + (kvB) + 16 + g * 4);           \
    rb2 = *reinterpret_cast<const f32x4*>(bp + (kvB) + 32 + g * 4);           \
    rm2 = *reinterpret_cast<const f32x4*>(mp + (kvB) + 32 + g * 4);           \
    rb3 = *reinterpret_cast<const f32x4*>(bp + (kvB) + 48 + g * 4);           \
    rm3 = *reinterpret_cast<const f32x4*>(mp + (kvB) + 48 + g * 4);           \
  } while (0)

// fold last iteration's raw loads into bm (zero-wait: barrier already drained vmcnt)
#define COMBINE do {                                                          \
    bm0 = (rb0 + rm0) * L2E; bm1 = (rb1 + rm1) * L2E;                         \
    bm2 = (rb2 + rm2) * L2E; bm3 = (rb3 + rm3) * L2E;                         \
  } while (0)

#define STAGE(kvB, buf) do {                                                                \
    load_lds16(Kp + (size_t)((kvB) + w * 16 + srow) * HD + ksrc,      &Ks[buf][(w * 2) * 512]);     \
    load_lds16(Vp + (size_t)(w * 16 + srow) * S_LEN + (kvB) + ksrc,   &Vs[buf][(w * 2) * 512]);     \
    load_lds16(Kp + (size_t)((kvB) + w * 16 + 8 + srow) * HD + ksrc,  &Ks[buf][(w * 2 + 1) * 512]); \
    load_lds16(Vp + (size_t)(w * 16 + 8 + srow) * S_LEN + (kvB) + ksrc, &Vs[buf][(w * 2 + 1) * 512]); \
  } while (0)

#define QK_COL(NN, SCN) do {                                                  \
    bf16x8 kf0_ = lds_swz_read(KSB_, (NN) * 16 + q, cbq);                     \
    bf16x8 kf1_ = lds_swz_read(KSB_, (NN) * 16 + q, 64 + cbq);                \
    f32x4 z_ = {};                                                            \
    z_ = mfma16(kf0_, qf0, z_);                                               \
    SCN = mfma16(kf1_, qf1, z_);                                              \
  } while (0)

#define BIAS_COL(SCN, BMN) do {                                               \
    SCN[0] = SCN[0] * SC + BMN[0];                                            \
    SCN[1] = SCN[1] * SC + BMN[1];                                            \
    SCN[2] = SCN[2] * SC + BMN[2];                                            \
    SCN[3] = SCN[3] * SC + BMN[3];                                            \
    mt_ = fmaxf(mt_, fmaxf(fmaxf(SCN[0], SCN[1]), fmaxf(SCN[2], SCN[3])));    \
  } while (0)

#define EXP_COL(SCN) do {                                                     \
    SCN[0] = EXP2F(SCN[0] - mn_); SCN[1] = EXP2F(SCN[1] - mn_);               \
    SCN[2] = EXP2F(SCN[2] - mn_); SCN[3] = EXP2F(SCN[3] - mn_);               \
  } while (0)

#define PWR_COL(NN, SCN) do {                                                 \
    u16x4 pk_;                                                                \
    pk_[0] = f2bf(SCN[0]); pk_[1] = f2bf(SCN[1]);                             \
    pk_[2] = f2bf(SCN[2]); pk_[3] = f2bf(SCN[3]);                             \
    const int colb_ = ((NN) * 16 + 4 * g) * 2;                                \
    *reinterpret_cast<u16x4*>(                                                \
        reinterpret_cast<char*>(Pw_) + (q << 7) + (colb_ ^ ((q & 7) << 4))) = pk_; \
  } while (0)

#define PV_COL(NN, ACCN) do {                                                 \
    bf16x8 vf0_ = lds_swz_read(VSB_, (NN) * 16 + q, cbq);                     \
    bf16x8 vf1_ = lds_swz_read(VSB_, (NN) * 16 + q, 64 + cbq);                \
    ACCN = mfma16(vf0_, pf0_, ACCN);                                          \
    ACCN = mfma16(vf1_, pf1_, ACCN);                                          \
  } while (0)

#define COMPUTE_TILE(KSB, VSB) do {                                           \
    const unsigned short* KSB_ = (KSB);                                       \
    const unsigned short* VSB_ = (VSB);                                       \
    f32x4 sc0_, sc1_, sc2_, sc3_;                                             \
    QK_COL(0, sc0_); QK_COL(1, sc1_); QK_COL(2, sc2_); QK_COL(3, sc3_);       \
    float mt_ = -3.0e38f;                                                     \
    BIAS_COL(sc0_, bm0); BIAS_COL(sc1_, bm1);                                 \
    BIAS_COL(sc2_, bm2); BIAS_COL(sc3_, bm3);                                 \
    mt_ = fmaxf(mt_, __shfl_xor(mt_, 16));                                    \
    mt_ = fmaxf(mt_, __shfl_xor(mt_, 32));                                    \
    const float mn_ = fmaxf(m_run, mt_);                                      \
    const float corr_ = EXP2F(m_run - mn_);                                   \
    m_run = mn_;                                                              \
    EXP_COL(sc0_); EXP_COL(sc1_); EXP_COL(sc2_); EXP_COL(sc3_);               \
    f32x4 ls4_ = sc0_ + sc1_ + sc2_ + sc3_;                                   \
    float ls_ = ls4_[0] + ls4_[1] + ls4_[2] + ls4_[3];                        \
    ls_ += __shfl_xor(ls_, 16);                                               \
    ls_ += __shfl_xor(ls_, 32);                                               \
    l_run = l_run * corr_ + ls_;                                              \
    acc0_ *= corr_; acc1_ *= corr_; acc2_ *= corr_; acc3_ *= corr_;           \
    unsigned short* Pw_ = Ps[w];                                              \
    PWR_COL(0, sc0_); PWR_COL(1, sc1_); PWR_COL(2, sc2_); PWR_COL(3, sc3_);   \
    bf16x8 pf0_ = lds_swz_read(Pw_, q, cbq);                                  \
    bf16x8 pf1_ = lds_swz_read(Pw_, q, 64 + cbq);                             \
    PV_COL(0, acc0_); PV_COL(1, acc1_); PV_COL(2, acc2_); PV_COL(3, acc3_);   \
  } while (0)

__global__ __launch_bounds__(256) __attribute__((amdgpu_waves_per_eu(3, 4)))
void attn_kernel(const unsigned short* __restrict__ Q,
                 const unsigned short* __restrict__ Kmat,
                 const unsigned short* __restrict__ Vt,
                 const float* __restrict__ rel_bias,
                 const float* __restrict__ mask,
                 unsigned short* __restrict__ ctx)
{
  __shared__ unsigned short Ks[2][64 * 64];
  __shared__ unsigned short Vs[2][64 * 64];
  __shared__ unsigned short Ps[4][16 * 64];

  // XCD-chunked bijective remap: 1024 = 8 XCDs x 128; b is fastest in logical id
  const int logical = (blockIdx.x & 7) * 128 + (blockIdx.x >> 3);
  const int b  = logical & 1;
  const int qt = (logical >> 1) & 31;
  const int h  = logical >> 6;

  const int lane = threadIdx.x & 63, w = threadIdx.x >> 6;
  const int q = lane & 15, g = lane >> 4;
  const size_t bh = (size_t)b * NH + h;
  const int qRow = qt * 64 + w * 16;
  const unsigned short* Qp = Q + (bh * S_LEN + qRow) * HD;
  bf16x8 qf0 = *reinterpret_cast<const bf16x8*>(Qp + (size_t)q * HD + g * 8);
  bf16x8 qf1 = *reinterpret_cast<const bf16x8*>(Qp + (size_t)q * HD + 32 + g * 8);

  const unsigned short* Kp = Kmat + bh * (size_t)S_LEN * HD;
  const unsigned short* Vp = Vt + bh * (size_t)HD * S_LEN;
  const float* bp = rel_bias + (size_t)h * S_LEN * S_LEN + (size_t)(qRow + q) * S_LEN;
  const float* mp = mask + (size_t)(qRow + q) * S_LEN;

  float m_run = -3.0e38f, l_run = 0.f;
  f32x4 acc0_ = {}, acc1_ = {}, acc2_ = {}, acc3_ = {};
  f32x4 rb0, rb1, rb2, rb3, rm0, rm1, rm2, rm3;
  f32x4 bm0, bm1, bm2, bm3;

  const float SC  = 0.125f * 1.44269504089f;  // head scale * log2(e)
  const float L2E = 1.44269504089f;

  const int srow = lane >> 3;
  const int ksrc = ((lane & 7) ^ srow) * 8;   // pre-swizzled global k-offset
  const int cbq = g << 4;

  // prologue: raw bias/mask tile0 + KV tile0 -> buf0
  LOAD_RAW(0);
  STAGE(0, 0);
  __syncthreads();

  for (int i = 0; i < 16; ++i) {
    const int t0 = 2 * i;
    COMBINE;                       // bm <- tile t0 (loads landed before barrier)
    LOAD_RAW((t0 + 1) * 64);       // raw <- tile t0+1 (covered by this compute)
    STAGE((t0 + 1) * 64, 1);
    COMPUTE_TILE(Ks[0], Vs[0]);
    __syncthreads();
    COMBINE;                       // bm <- tile t0+1
    if (i < 15) {
      LOAD_RAW((t0 + 2) * 64);
      STAGE((t0 + 2) * 64, 0);
    }
    COMPUTE_TILE(Ks[1], Vs[1]);
    __syncthreads();
  }

  // epilogue: normalize, redistribute through per-wave LDS, coalesced 16B stores
  const float inv = 1.0f / l_run;
  acc0_ *= inv; acc1_ *= inv; acc2_ *= inv; acc3_ *= inv;
  unsigned short* Pw_ = Ps[w];
  PWR_COL(0, acc0_); PWR_COL(1, acc1_); PWR_COL(2, acc2_); PWR_COL(3, acc3_);
  bf16x8 c0 = lds_swz_read(Pw_, q, g << 4);
  bf16x8 c1 = lds_swz_read(Pw_, q, 64 + (g << 4));
  unsigned short* cp = ctx + ((size_t)b * S_LEN + qRow + q) * DM + h * HD;
  *reinterpret_cast<bf16x8*>(cp + 8 * g) = c0;
  *reinterpret_cast<bf16x8*>(cp + 32 + 8 * g) = c1;
}

extern "C" void kernel_launch(void* const* d_in, const int* in_sizes, int n_in,
                              void* d_out, int out_size, void* d_ws, size_t ws_size,
                              hipStream_t stream) {
  (void)in_sizes; (void)n_in; (void)out_size; (void)ws_size;
  const float* x  = (const float*)d_in[0];
  const float* rb = (const float*)d_in[1];
  const float* mk = (const float*)d_in[2];
  const float* Wq = (const float*)d_in[3];
  const float* bq = (const float*)d_in[4];
  const float* Wk = (const float*)d_in[5];
  const float* bk = (const float*)d_in[6];
  const float* Wv = (const float*)d_in[7];
  const float* bv = (const float*)d_in[8];
  const float* Wo = (const float*)d_in[9];
  const float* bo = (const float*)d_in[10];
  float* out = (float*)d_out;

  unsigned short* ws  = (unsigned short*)d_ws;
  unsigned short* xb  = ws;                       // 4M elems
  unsigned short* wqb = ws + (1L << 22);          // 1M
  unsigned short* wkb = wqb + (1L << 20);
  unsigned short* wvb = wkb + (1L << 20);
  unsigned short* wob = wvb + (1L << 20);
  unsigned short* Qw  = wob + (1L << 20);         // 4M [B,H,S,64]
  unsigned short* Kw  = Qw + (1L << 22);          // 4M [B,H,S,64]
  unsigned short* Vtw = Kw + (1L << 22);          // 4M [B,H,64,S]
  unsigned short* ctx = Vtw + (1L << 22);         // 4M [B,S,DM]

  prep_kernel<<<8192, 256, 0, stream>>>(x, Wq, Wk, Wv, Wo, ws);
  gemm_bt_kernel<0><<<dim3(24, 32), 256, 0, stream>>>(
      xb, wqb, wkb, wvb, bq, bk, bv, Qw, Kw, Vtw, nullptr);
  attn_kernel<<<1024, 256, 0, stream>>>(Qw, Kw, Vtw, rb, mk, ctx);
  gemm_bt_kernel<1><<<dim3(8, 32), 256, 0, stream>>>(
      ctx, wob, nullptr, nullptr, bo, nullptr, nullptr, nullptr, nullptr, nullptr, out);
}